// Round 11
// baseline (344.874 us; speedup 1.0000x reference)
//
#include <hip/hip_runtime.h>
#include <stdint.h>

// R19: QT=128 per block via 512 threads / 8 waves (grid 1024->512). TLP
// preserved: 2 blocks/CU x 8 waves = 16 waves/CU (same as R18's 4x4), but
// each 24KB staged tile now serves 128 q-rows: staging issue per wave 6->3
// chunks, total staged traffic 1.57GB->786MB, total barrier-iterations
// halved. Per-wave work/registers unchanged; same RNG indices -> bit-exact.
// Prepass = R18's (swizzled sT, neutral but harmless). Fused internals =
// R18's (DPP softmax, RNG slab-skip, all-skip PV, setprio).

namespace {

constexpr int Bb  = 32;
constexpr int SQ  = 2048;
constexpr int SKV = 2048;
constexpr int DH  = 128;
constexpr int KT  = 32;
constexpr int NKT = SKV / KT;          // 64
constexpr int TILE_F16 = 12288;        // Khi 4096 | Klo 4096 | Vt 4096 (f16 elems)
constexpr size_t WS_NEED = (size_t)Bb * NKT * TILE_F16 * 2;  // 50,331,648 B
constexpr int PSTR = KT + 8;           // 40

typedef _Float16 f16x8 __attribute__((ext_vector_type(8)));
typedef _Float16 f16x4 __attribute__((ext_vector_type(4)));
typedef float    f32x4 __attribute__((ext_vector_type(4)));

__device__ __forceinline__ uint32_t rotl32(uint32_t x, int d) {
  return (x << d) | (x >> (32 - d));
}

// JAX threefry2x32, key=(0,42), counter=(0,i); partitionable bits = x0^x1.
__device__ __forceinline__ uint32_t jax_random_bits(uint32_t i) {
  constexpr uint32_t K0 = 0u;
  constexpr uint32_t K1 = 42u;
  constexpr uint32_t K2 = 0x1BD11BDAu ^ K0 ^ K1;
  uint32_t x0 = K0;
  uint32_t x1 = i + K1;
#define TF4(a,b,c,d) \
  x0 += x1; x1 = rotl32(x1,a); x1 ^= x0; \
  x0 += x1; x1 = rotl32(x1,b); x1 ^= x0; \
  x0 += x1; x1 = rotl32(x1,c); x1 ^= x0; \
  x0 += x1; x1 = rotl32(x1,d); x1 ^= x0;
  TF4(13,15,26,6)   x0 += K1; x1 += K2 + 1u;
  TF4(17,29,16,24)  x0 += K2; x1 += K0 + 2u;
  TF4(13,15,26,6)   x0 += K0; x1 += K1 + 3u;
  TF4(17,29,16,24)  x0 += K1; x1 += K2 + 4u;
  TF4(13,15,26,6)   x0 += K2; x1 += K0 + 5u;
#undef TF4
  return x0 ^ x1;
}

// keep <=> uniform < 0.7f  <=>  (bits>>9) < 0x59999A  (exact)
__device__ __forceinline__ bool jax_keep_bits(uint32_t bits) {
  return (bits >> 9) < 0x0059999Au;
}

__device__ __forceinline__ _Float16 hi16(float x) { return (_Float16)x; }
__device__ __forceinline__ _Float16 lo16(float x) {
  return (_Float16)(x - (float)((_Float16)x));
}

// DPP lane-permute (VALU pipe; stays within 16-lane row, all sources active
// under the row-uniform branch). bound_ctrl=1, full row/bank masks.
template <int CTRL>
__device__ __forceinline__ float dppf(float v) {
  return __int_as_float(__builtin_amdgcn_update_dpp(
      0, __float_as_int(v), CTRL, 0xF, 0xF, true));
}
__device__ __forceinline__ float row16_max(float x) {
  x = fmaxf(x, dppf<0xB1>(x));
  x = fmaxf(x, dppf<0x4E>(x));
  x = fmaxf(x, dppf<0x141>(x));
  x = fmaxf(x, dppf<0x140>(x));
  return x;
}
__device__ __forceinline__ float row16_sum(float x) {
  x += dppf<0xB1>(x);
  x += dppf<0x4E>(x);
  x += dppf<0x141>(x);
  x += dppf<0x140>(x);
  return x;
}

// prepass sT column swizzle: float4-slot XOR (includes row bit 3).
__device__ __forceinline__ int swz8(int row) { return (row + (row >> 3)) & 7; }

} // namespace

// ------------- prepass: one block per (b,kt) 32-row tile, coalesced -------------
__global__ __launch_bounds__(256) void prep_tile(const float* __restrict__ Kg,
                                                 const float* __restrict__ Vg,
                                                 _Float16* __restrict__ ws) {
  __shared__ alignas(16) float sT[KT][DH + 4];   // 16.9 KB, reused K then V

  const int tid  = threadIdx.x;
  const int b    = blockIdx.x >> 6;
  const int kt   = blockIdx.x & 63;
  _Float16* tile = ws + (size_t)(b * NKT + kt) * TILE_F16;

  // ---- phase K: coalesced load -> LDS (32 rows x 32 float4, swizzled cols)
  {
    const float* kb = Kg + ((size_t)b * SKV + kt * KT) * DH;
#pragma unroll
    for (int rep = 0; rep < 4; ++rep) {
      const int idx = tid + 256 * rep;
      const int row = idx >> 5;
      const int c4  = idx & 31;
      *reinterpret_cast<float4*>(&sT[row][4 * (c4 ^ swz8(row))]) =
          *reinterpret_cast<const float4*>(kb + (size_t)row * DH + 4 * c4);
    }
  }
  __syncthreads();
  // K hi/lo fragment-linear writes: frag f = ks*2+ct (0..7)
#pragma unroll
  for (int rep = 0; rep < 2; ++rep) {
    const int task = tid + 256 * rep;     // 0..511
    const int lane = task & 63;
    const int f    = task >> 6;           // 0..7
    const int ks   = f >> 1;
    const int ct   = f & 1;
    const int cl   = lane & 15;
    const int g8   = (lane >> 4) * 8;
    const int rowk = ct * 16 + cl;
    const int c4a  = ks * 8 + (g8 >> 2);  // first float4 slot of the 8 floats
    const float4 xa = *reinterpret_cast<const float4*>(
        &sT[rowk][4 * (c4a ^ swz8(rowk))]);
    const float4 xb = *reinterpret_cast<const float4*>(
        &sT[rowk][4 * ((c4a + 1) ^ swz8(rowk))]);
    const float xs[8] = {xa.x, xa.y, xa.z, xa.w, xb.x, xb.y, xb.z, xb.w};
    f16x8 h, l;
#pragma unroll
    for (int j = 0; j < 8; ++j) { h[j] = hi16(xs[j]); l[j] = lo16(xs[j]); }
    *reinterpret_cast<f16x8*>(tile + f * 512 + lane * 8)        = h;
    *reinterpret_cast<f16x8*>(tile + 4096 + f * 512 + lane * 8) = l;
  }
  __syncthreads();

  // ---- phase V (same swizzled layout)
  {
    const float* vb = Vg + ((size_t)b * SKV + kt * KT) * DH;
#pragma unroll
    for (int rep = 0; rep < 4; ++rep) {
      const int idx = tid + 256 * rep;
      const int row = idx >> 5;
      const int c4  = idx & 31;
      *reinterpret_cast<float4*>(&sT[row][4 * (c4 ^ swz8(row))]) =
          *reinterpret_cast<const float4*>(vb + (size_t)row * DH + 4 * c4);
    }
  }
  __syncthreads();
  // V^T fragment-linear: frag = dt (0..7), elem j = V[g8+j][dt*16+cl]
#pragma unroll
  for (int rep = 0; rep < 2; ++rep) {
    const int task = tid + 256 * rep;
    const int lane = task & 63;
    const int dt   = task >> 6;           // 0..7
    const int cl   = lane & 15;
    const int g8   = (lane >> 4) * 8;
    const int c4v  = dt * 4 + (cl >> 2);  // float4 slot of col dt*16+cl
    f16x8 w;
#pragma unroll
    for (int j = 0; j < 8; ++j) {
      const int rowv = g8 + j;
      w[j] = (_Float16)sT[rowv][4 * (c4v ^ swz8(rowv)) + (cl & 3)];
    }
    *reinterpret_cast<f16x8*>(tile + 8192 + dt * 512 + lane * 8) = w;
  }
}

// ------------- main fused kernel: QT=128, 8 waves, KT=32 -------------
__global__ __launch_bounds__(512, 4) void fused_attn5(
    const float* __restrict__ Qg, const _Float16* __restrict__ Wk,
    const float* __restrict__ Sg, float* __restrict__ Og)
{
  __shared__ alignas(16) _Float16 sStage[TILE_F16];   // 24 KB: Khi|Klo|Vt
  __shared__ alignas(16) _Float16 sP[8][16][PSTR];    // 10.2 KB (wave-private)

  const int tid  = threadIdx.x;
  const int wid  = tid >> 6;              // 0..7
  const int lane = tid & 63;
  const int cl   = lane & 15;
  const int g8   = (lane >> 4) * 8;
  const int r0   = (lane >> 4) * 4;

  const int b  = blockIdx.x >> 4;         // grid = 32 * 16
  const int q0 = (blockIdx.x & 15) * 128;
  const float scale = Sg[b];

  // Q A-fragments (hi/lo) in registers: rows q0+wid*16+cl
  f16x8 qhi[4], qlo[4];
  {
    const float* qp = Qg + ((size_t)b * SQ + q0 + wid * 16 + cl) * DH + g8;
#pragma unroll
    for (int ks = 0; ks < 4; ++ks) {
      const float4 a0 = *reinterpret_cast<const float4*>(qp + 32 * ks);
      const float4 a1 = *reinterpret_cast<const float4*>(qp + 32 * ks + 4);
      const float xs[8] = {a0.x, a0.y, a0.z, a0.w, a1.x, a1.y, a1.z, a1.w};
#pragma unroll
      for (int j = 0; j < 8; ++j) { qhi[ks][j] = hi16(xs[j]); qlo[ks][j] = lo16(xs[j]); }
    }
  }

  float m_run[4], l_run[4], alpha[4];
  bool  zknown[4];    // sP row currently all-zero (skip redundant zero-fills)
  f32x4 oacc[8];
#pragma unroll
  for (int i = 0; i < 4; ++i) {
    m_run[i] = -INFINITY; l_run[i] = 0.0f; zknown[i] = false;
  }
#pragma unroll
  for (int dt = 0; dt < 8; ++dt) oacc[dt] = (f32x4){0.f, 0.f, 0.f, 0.f};

  for (int kt = 0; kt < NKT; ++kt) {
    __syncthreads();   // prev iter's reads of sStage done

    // ---- DMA stage 24 KB: 24 chunks of 1 KB, 3 per wave (8 waves)
    const uint32_t* tsrc =
        reinterpret_cast<const uint32_t*>(Wk + (size_t)(b * NKT + kt) * TILE_F16);
#pragma unroll
    for (int c = 0; c < 3; ++c) {
      const int j = wid + 8 * c;
      __builtin_amdgcn_global_load_lds(tsrc + j * 256 + lane * 4,
          reinterpret_cast<uint32_t*>(&sStage[j * 512]), 16, 0, 0);
    }
    __syncthreads();   // tile visible

    // ---- S = Q K^T (fp16 hi/lo, fp32 accum): 16x32 per wave
    f32x4 sacc[2];
    __builtin_amdgcn_s_setprio(1);
#pragma unroll
    for (int ct = 0; ct < 2; ++ct) {
      sacc[ct] = (f32x4){0.f, 0.f, 0.f, 0.f};
#pragma unroll
      for (int ks = 0; ks < 4; ++ks) {
        const int f = ks * 2 + ct;
        const f16x8 bhi = *reinterpret_cast<const f16x8*>(&sStage[f * 512 + lane * 8]);
        const f16x8 blo = *reinterpret_cast<const f16x8*>(&sStage[4096 + f * 512 + lane * 8]);
        sacc[ct] = __builtin_amdgcn_mfma_f32_16x16x32_f16(qhi[ks], bhi, sacc[ct], 0, 0, 0);
        sacc[ct] = __builtin_amdgcn_mfma_f32_16x16x32_f16(qlo[ks], bhi, sacc[ct], 0, 0, 0);
        sacc[ct] = __builtin_amdgcn_mfma_f32_16x16x32_f16(qhi[ks], blo, sacc[ct], 0, 0, 0);
      }
    }
    __builtin_amdgcn_s_setprio(0);

    // ---- online softmax, per-row fast-path; DPP reductions (VALU pipe)
    bool anyalpha = false;
    bool tk[4];
#pragma unroll
    for (int i = 0; i < 4; ++i) {
      const float mraw = row16_max(fmaxf(sacc[0][i], sacc[1][i]));
      const float mt = mraw * scale;

      tk[i] = (mt >= m_run[i] - 9.21f);   // 16-lane-group-uniform per row
      if (tk[i]) {
        // alpha: exp only on a new record; catch-up rows give exp(0)==1 exactly
        float mnew;
        if (mt > m_run[i]) {
          alpha[i] = __expf(m_run[i] - mt);
          mnew = mt;
          m_run[i] = mt;
          anyalpha |= (alpha[i] != 1.0f);
        } else {
          alpha[i] = 1.0f;
          mnew = m_run[i];
        }
        const int qrow = q0 + wid * 16 + r0 + i;
        const uint32_t rowbase =
            ((uint32_t)b * (uint32_t)SQ + (uint32_t)qrow) * (uint32_t)SKV
            + (uint32_t)(kt * KT);

        const float t0 = sacc[0][i] * scale - mnew;
        const float t1 = sacc[1][i] * scale - mnew;
        const float p0 = __expf(t0);
        const float p1 = __expf(t1);
        const float ps = row16_sum(p0 + p1);
        l_run[i] = l_run[i] * alpha[i] + ps;

        // dropout writes with exact slab-tiny skip: t < -17.75 ->
        // (f16)(p/0.7) == 0 kept OR dropped -> threefry dead.
        if (__any(t0 >= -17.75f)) {
          const uint32_t bits = jax_random_bits(rowbase + (uint32_t)cl);
          sP[wid][r0 + i][cl] = jax_keep_bits(bits)
                                    ? (_Float16)(p0 * (1.0f / 0.7f))
                                    : (_Float16)0.0f;
        } else {
          sP[wid][r0 + i][cl] = (_Float16)0.0f;
        }
        if (__any(t1 >= -17.75f)) {
          const uint32_t bits = jax_random_bits(rowbase + (uint32_t)(16 + cl));
          sP[wid][r0 + i][16 + cl] = jax_keep_bits(bits)
                                         ? (_Float16)(p1 * (1.0f / 0.7f))
                                         : (_Float16)0.0f;
        } else {
          sP[wid][r0 + i][16 + cl] = (_Float16)0.0f;
        }
        zknown[i] = false;   // row now holds (possibly) nonzero data
      } else {
        alpha[i] = 1.0f;
      }
    }

    // ---- wave-uniform all-skip: P-tile exactly zero -> PV adds nothing.
    const int myAllSkip = !(tk[0] || tk[1] || tk[2] || tk[3]);
    if (!__all(myAllSkip)) {
      // zero-fill skipped rows only if not already zero from a prior iter
#pragma unroll
      for (int i = 0; i < 4; ++i) {
        if (!tk[i] && !zknown[i]) {
#pragma unroll
          for (int ct = 0; ct < 2; ++ct)
            sP[wid][r0 + i][16 * ct + cl] = (_Float16)0.0f;
          zknown[i] = true;
        }
      }

      if (anyalpha) {
#pragma unroll
        for (int dt = 0; dt < 8; ++dt)
#pragma unroll
          for (int i = 0; i < 4; ++i) oacc[dt][i] *= alpha[i];
      }

      // ---- O += P V (k=32, one MFMA per dt); sP wave-private
      const f16x8 pa = *reinterpret_cast<const f16x8*>(&sP[wid][cl][g8]);
      __builtin_amdgcn_s_setprio(1);
#pragma unroll
      for (int dt = 0; dt < 8; ++dt) {
        const f16x8 bv = *reinterpret_cast<const f16x8*>(
            &sStage[8192 + dt * 512 + lane * 8]);
        oacc[dt] = __builtin_amdgcn_mfma_f32_16x16x32_f16(pa, bv, oacc[dt], 0, 0, 0);
      }
      __builtin_amdgcn_s_setprio(0);
    }
  }

  // ---- epilogue
#pragma unroll
  for (int i = 0; i < 4; ++i) {
    const float inv_l = 1.0f / l_run[i];
    float* op = Og + ((size_t)b * SQ + (size_t)(q0 + wid * 16 + r0 + i)) * DH + cl;
#pragma unroll
    for (int dt = 0; dt < 8; ++dt)
      op[16 * dt] = oacc[dt][i] * inv_l;
  }
}

// ---------------- fallback (self-staging, QT=64, KT=64) ----------------
namespace {
constexpr int FKT  = 64;
constexpr int KSTR = DH + 8;
constexpr int VSTR = FKT + 8;
constexpr int FPSTR = FKT + 8;
}

__global__ __launch_bounds__(256, 2) void fused_attn_fb(
    const float* __restrict__ Qg, const float* __restrict__ Kg,
    const float* __restrict__ Vg, const float* __restrict__ Sg,
    float* __restrict__ Og)
{
  __shared__ alignas(16) _Float16 sKhi[FKT][KSTR];
  __shared__ alignas(16) _Float16 sKlo[FKT][KSTR];
  __shared__ alignas(16) _Float16 sVt[DH][VSTR];
  __shared__ alignas(16) _Float16 sP[4][16][FPSTR];

  const int tid  = threadIdx.x;
  const int wid  = tid >> 6;
  const int lane = tid & 63;
  const int cl   = lane & 15;
  const int g8   = (lane >> 4) * 8;
  const int r0   = (lane >> 4) * 4;

  const int b  = blockIdx.x >> 5;
  const int q0 = (blockIdx.x & 31) * 64;
  const float scale = Sg[b];

  f16x8 qhi[4], qlo[4];
  {
    const float* qp = Qg + ((size_t)b * SQ + q0 + wid * 16 + cl) * DH + g8;
#pragma unroll
    for (int ks = 0; ks < 4; ++ks) {
      const float4 a0 = *reinterpret_cast<const float4*>(qp + 32 * ks);
      const float4 a1 = *reinterpret_cast<const float4*>(qp + 32 * ks + 4);
      const float xs[8] = {a0.x, a0.y, a0.z, a0.w, a1.x, a1.y, a1.z, a1.w};
#pragma unroll
      for (int j = 0; j < 8; ++j) { qhi[ks][j] = hi16(xs[j]); qlo[ks][j] = lo16(xs[j]); }
    }
  }

  float m_run[4], l_run[4], alpha[4];
  f32x4 oacc[8];
#pragma unroll
  for (int i = 0; i < 4; ++i) { m_run[i] = -INFINITY; l_run[i] = 0.0f; }
#pragma unroll
  for (int dt = 0; dt < 8; ++dt) oacc[dt] = (f32x4){0.f, 0.f, 0.f, 0.f};

  for (int k0 = 0; k0 < SKV; k0 += FKT) {
    __syncthreads();
#pragma unroll
    for (int rep = 0; rep < 8; ++rep) {
      const int idx = tid + 256 * rep;
      const int row = idx >> 5;
      const int c4  = idx & 31;
      const float4 t = *reinterpret_cast<const float4*>(
          Kg + ((size_t)b * SKV + k0 + row) * DH + 4 * c4);
      f16x4 h4, l4;
      h4[0] = hi16(t.x); l4[0] = lo16(t.x);
      h4[1] = hi16(t.y); l4[1] = lo16(t.y);
      h4[2] = hi16(t.z); l4[2] = lo16(t.z);
      h4[3] = hi16(t.w); l4[3] = lo16(t.w);
      *reinterpret_cast<f16x4*>(&sKhi[row][4 * c4]) = h4;
      *reinterpret_cast<f16x4*>(&sKlo[row][4 * c4]) = l4;
    }
#pragma unroll
    for (int rep = 0; rep < 2; ++rep) {
      const int u  = tid + 256 * rep;
      const int du = u & 31;
      const int ku = u >> 5;
      const float* vb = Vg + ((size_t)b * SKV + k0 + 4 * ku) * DH + 4 * du;
      float4 t[4];
#pragma unroll
      for (int j = 0; j < 4; ++j)
        t[j] = *reinterpret_cast<const float4*>(vb + (size_t)j * DH);
#pragma unroll
      for (int dd = 0; dd < 4; ++dd) {
        const float v0 = (&t[0].x)[dd], v1 = (&t[1].x)[dd],
                    v2 = (&t[2].x)[dd], v3 = (&t[3].x)[dd];
        f16x4 w4 = {(_Float16)v0, (_Float16)v1, (_Float16)v2, (_Float16)v3};
        *reinterpret_cast<f16x4*>(&sVt[4 * du + dd][4 * ku]) = w4;
      }
    }
    __syncthreads();

    f32x4 sacc[4];
#pragma unroll
    for (int ct = 0; ct < 4; ++ct) {
      sacc[ct] = (f32x4){0.f, 0.f, 0.f, 0.f};
#pragma unroll
      for (int ks = 0; ks < 4; ++ks) {
        const f16x8 bhi = *reinterpret_cast<const f16x8*>(&sKhi[16 * ct + cl][32 * ks + g8]);
        const f16x8 blo = *reinterpret_cast<const f16x8*>(&sKlo[16 * ct + cl][32 * ks + g8]);
        sacc[ct] = __builtin_amdgcn_mfma_f32_16x16x32_f16(qhi[ks], bhi, sacc[ct], 0, 0, 0);
        sacc[ct] = __builtin_amdgcn_mfma_f32_16x16x32_f16(qlo[ks], bhi, sacc[ct], 0, 0, 0);
        sacc[ct] = __builtin_amdgcn_mfma_f32_16x16x32_f16(qhi[ks], blo, sacc[ct], 0, 0, 0);
      }
    }

    bool anyalpha = false;
#pragma unroll
    for (int i = 0; i < 4; ++i) {
      float mraw = fmaxf(fmaxf(sacc[0][i], sacc[1][i]), fmaxf(sacc[2][i], sacc[3][i]));
#pragma unroll
      for (int off = 8; off >= 1; off >>= 1)
        mraw = fmaxf(mraw, __shfl_xor(mraw, off, 64));
      const float mt = mraw * scale;
      if (mt >= m_run[i] - 9.21f) {
        const float mnew = fmaxf(m_run[i], mt);
        alpha[i] = __expf(m_run[i] - mnew);
        m_run[i] = mnew;
        const int qrow = q0 + wid * 16 + r0 + i;
        const uint32_t rowbase =
            ((uint32_t)b * (uint32_t)SQ + (uint32_t)qrow) * (uint32_t)SKV + (uint32_t)k0;
        float ps = 0.0f;
#pragma unroll
        for (int ct = 0; ct < 4; ++ct) {
          const float p = __expf(sacc[ct][i] * scale - mnew);
          ps += p;
          const bool keep = jax_keep_bits(jax_random_bits(rowbase + (uint32_t)(16 * ct + cl)));
          sP[wid][r0 + i][16 * ct + cl] = keep ? (_Float16)(p * (1.0f / 0.7f))
                                               : (_Float16)0.0f;
        }
#pragma unroll
        for (int off = 8; off >= 1; off >>= 1)
          ps += __shfl_xor(ps, off, 64);
        l_run[i] = l_run[i] * alpha[i] + ps;
        anyalpha |= (alpha[i] != 1.0f);
      } else {
        alpha[i] = 1.0f;
#pragma unroll
        for (int ct = 0; ct < 4; ++ct)
          sP[wid][r0 + i][16 * ct + cl] = (_Float16)0.0f;
      }
    }

    if (anyalpha) {
#pragma unroll
      for (int dt = 0; dt < 8; ++dt)
#pragma unroll
        for (int i = 0; i < 4; ++i) oacc[dt][i] *= alpha[i];
    }
#pragma unroll
    for (int ks2 = 0; ks2 < 2; ++ks2) {
      const f16x8 pa = *reinterpret_cast<const f16x8*>(&sP[wid][cl][32 * ks2 + g8]);
#pragma unroll
      for (int dt = 0; dt < 8; ++dt) {
        const f16x8 bv = *reinterpret_cast<const f16x8*>(&sVt[16 * dt + cl][32 * ks2 + g8]);
        oacc[dt] = __builtin_amdgcn_mfma_f32_16x16x32_f16(pa, bv, oacc[dt], 0, 0, 0);
      }
    }
  }

#pragma unroll
  for (int i = 0; i < 4; ++i) {
    const float inv_l = 1.0f / l_run[i];
    float* op = Og + ((size_t)b * SQ + (size_t)(q0 + wid * 16 + r0 + i)) * DH + cl;
#pragma unroll
    for (int dt = 0; dt < 8; ++dt)
      op[16 * dt] = oacc[dt][i] * inv_l;
  }
}

extern "C" void kernel_launch(void* const* d_in, const int* in_sizes, int n_in,
                              void* d_out, int out_size, void* d_ws, size_t ws_size,
                              hipStream_t stream) {
  (void)in_sizes; (void)n_in; (void)out_size;
  const float* q  = (const float*)d_in[0];
  const float* k  = (const float*)d_in[1];
  const float* v  = (const float*)d_in[2];
  const float* sc = (const float*)d_in[3];
  float* out = (float*)d_out;

  if (ws_size >= WS_NEED) {
    _Float16* ws = (_Float16*)d_ws;
    prep_tile<<<dim3(Bb * NKT), dim3(256), 0, stream>>>(k, v, ws);
    fused_attn5<<<dim3(Bb * (SQ / 128)), dim3(512), 0, stream>>>(q, ws, sc, out);
  } else {
    fused_attn_fb<<<dim3(Bb * (SQ / 64)), dim3(256), 0, stream>>>(q, k, v, sc, out);
  }
}

// Round 12
// 319.741 us; speedup vs baseline: 1.0786x; 1.0786x over previous
//
#include <hip/hip_runtime.h>
#include <stdint.h>

// R20 == R18 verbatim (regression recovery). R19's QT=128/8-wave falsifier
// triggered (226.5->242us): 8-wave barrier convergence + only 2 independent
// blocks/CU outweighed halved staging/barrier count. Structure space is now
// pinned from five directions (R9/R10/R11/R13/R19 all lost): the optimum is
// {4x 4-wave blocks/CU, 2 barriers/iter, 24KB single-buffer stage}. All wins
// came from serial-path work elimination: R12 all-skip, R16 exact RNG
// slab-skip, R17 DPP softmax reductions. R18 = that configuration.

namespace {

constexpr int Bb  = 32;
constexpr int SQ  = 2048;
constexpr int SKV = 2048;
constexpr int DH  = 128;
constexpr int KT  = 32;
constexpr int NKT = SKV / KT;          // 64
constexpr int TILE_F16 = 12288;        // Khi 4096 | Klo 4096 | Vt 4096 (f16 elems)
constexpr size_t WS_NEED = (size_t)Bb * NKT * TILE_F16 * 2;  // 50,331,648 B
constexpr int PSTR = KT + 8;           // 40

typedef _Float16 f16x8 __attribute__((ext_vector_type(8)));
typedef _Float16 f16x4 __attribute__((ext_vector_type(4)));
typedef float    f32x4 __attribute__((ext_vector_type(4)));

__device__ __forceinline__ uint32_t rotl32(uint32_t x, int d) {
  return (x << d) | (x >> (32 - d));
}

// JAX threefry2x32, key=(0,42), counter=(0,i); partitionable bits = x0^x1.
__device__ __forceinline__ uint32_t jax_random_bits(uint32_t i) {
  constexpr uint32_t K0 = 0u;
  constexpr uint32_t K1 = 42u;
  constexpr uint32_t K2 = 0x1BD11BDAu ^ K0 ^ K1;
  uint32_t x0 = K0;
  uint32_t x1 = i + K1;
#define TF4(a,b,c,d) \
  x0 += x1; x1 = rotl32(x1,a); x1 ^= x0; \
  x0 += x1; x1 = rotl32(x1,b); x1 ^= x0; \
  x0 += x1; x1 = rotl32(x1,c); x1 ^= x0; \
  x0 += x1; x1 = rotl32(x1,d); x1 ^= x0;
  TF4(13,15,26,6)   x0 += K1; x1 += K2 + 1u;
  TF4(17,29,16,24)  x0 += K2; x1 += K0 + 2u;
  TF4(13,15,26,6)   x0 += K0; x1 += K1 + 3u;
  TF4(17,29,16,24)  x0 += K1; x1 += K2 + 4u;
  TF4(13,15,26,6)   x0 += K2; x1 += K0 + 5u;
#undef TF4
  return x0 ^ x1;
}

// keep <=> uniform < 0.7f  <=>  (bits>>9) < 0x59999A  (exact)
__device__ __forceinline__ bool jax_keep_bits(uint32_t bits) {
  return (bits >> 9) < 0x0059999Au;
}

__device__ __forceinline__ _Float16 hi16(float x) { return (_Float16)x; }
__device__ __forceinline__ _Float16 lo16(float x) {
  return (_Float16)(x - (float)((_Float16)x));
}

// DPP lane-permute (VALU pipe; stays within 16-lane row, all sources active
// under the row-uniform branch). bound_ctrl=1, full row/bank masks.
template <int CTRL>
__device__ __forceinline__ float dppf(float v) {
  return __int_as_float(__builtin_amdgcn_update_dpp(
      0, __float_as_int(v), CTRL, 0xF, 0xF, true));
}
__device__ __forceinline__ float row16_max(float x) {
  x = fmaxf(x, dppf<0xB1>(x));
  x = fmaxf(x, dppf<0x4E>(x));
  x = fmaxf(x, dppf<0x141>(x));
  x = fmaxf(x, dppf<0x140>(x));
  return x;
}
__device__ __forceinline__ float row16_sum(float x) {
  x += dppf<0xB1>(x);
  x += dppf<0x4E>(x);
  x += dppf<0x141>(x);
  x += dppf<0x140>(x);
  return x;
}

// prepass sT column swizzle: float4-slot XOR. Includes row bit 3 so rows
// {j, 8+j, 16+j, 24+j} (which alias to the same banks at stride 132) spread.
__device__ __forceinline__ int swz8(int row) { return (row + (row >> 3)) & 7; }

} // namespace

// ------------- prepass: one block per (b,kt) 32-row tile, coalesced -------------
__global__ __launch_bounds__(256) void prep_tile(const float* __restrict__ Kg,
                                                 const float* __restrict__ Vg,
                                                 _Float16* __restrict__ ws) {
  __shared__ alignas(16) float sT[KT][DH + 4];   // 16.9 KB, reused K then V

  const int tid  = threadIdx.x;
  const int b    = blockIdx.x >> 6;
  const int kt   = blockIdx.x & 63;
  _Float16* tile = ws + (size_t)(b * NKT + kt) * TILE_F16;

  // ---- phase K: coalesced load -> LDS (32 rows x 32 float4, swizzled cols)
  {
    const float* kb = Kg + ((size_t)b * SKV + kt * KT) * DH;
#pragma unroll
    for (int rep = 0; rep < 4; ++rep) {
      const int idx = tid + 256 * rep;
      const int row = idx >> 5;
      const int c4  = idx & 31;
      *reinterpret_cast<float4*>(&sT[row][4 * (c4 ^ swz8(row))]) =
          *reinterpret_cast<const float4*>(kb + (size_t)row * DH + 4 * c4);
    }
  }
  __syncthreads();
  // K hi/lo fragment-linear writes: frag f = ks*2+ct (0..7)
#pragma unroll
  for (int rep = 0; rep < 2; ++rep) {
    const int task = tid + 256 * rep;     // 0..511
    const int lane = task & 63;
    const int f    = task >> 6;           // 0..7
    const int ks   = f >> 1;
    const int ct   = f & 1;
    const int cl   = lane & 15;
    const int g8   = (lane >> 4) * 8;
    const int rowk = ct * 16 + cl;
    const int c4a  = ks * 8 + (g8 >> 2);  // first float4 slot of the 8 floats
    const float4 xa = *reinterpret_cast<const float4*>(
        &sT[rowk][4 * (c4a ^ swz8(rowk))]);
    const float4 xb = *reinterpret_cast<const float4*>(
        &sT[rowk][4 * ((c4a + 1) ^ swz8(rowk))]);
    const float xs[8] = {xa.x, xa.y, xa.z, xa.w, xb.x, xb.y, xb.z, xb.w};
    f16x8 h, l;
#pragma unroll
    for (int j = 0; j < 8; ++j) { h[j] = hi16(xs[j]); l[j] = lo16(xs[j]); }
    *reinterpret_cast<f16x8*>(tile + f * 512 + lane * 8)        = h;
    *reinterpret_cast<f16x8*>(tile + 4096 + f * 512 + lane * 8) = l;
  }
  __syncthreads();

  // ---- phase V (same swizzled layout)
  {
    const float* vb = Vg + ((size_t)b * SKV + kt * KT) * DH;
#pragma unroll
    for (int rep = 0; rep < 4; ++rep) {
      const int idx = tid + 256 * rep;
      const int row = idx >> 5;
      const int c4  = idx & 31;
      *reinterpret_cast<float4*>(&sT[row][4 * (c4 ^ swz8(row))]) =
          *reinterpret_cast<const float4*>(vb + (size_t)row * DH + 4 * c4);
    }
  }
  __syncthreads();
  // V^T fragment-linear: frag = dt (0..7), elem j = V[g8+j][dt*16+cl]
#pragma unroll
  for (int rep = 0; rep < 2; ++rep) {
    const int task = tid + 256 * rep;
    const int lane = task & 63;
    const int dt   = task >> 6;           // 0..7
    const int cl   = lane & 15;
    const int g8   = (lane >> 4) * 8;
    const int c4v  = dt * 4 + (cl >> 2);  // float4 slot of col dt*16+cl
    f16x8 w;
#pragma unroll
    for (int j = 0; j < 8; ++j) {
      const int rowv = g8 + j;
      w[j] = (_Float16)sT[rowv][4 * (c4v ^ swz8(rowv)) + (cl & 3)];
    }
    *reinterpret_cast<f16x8*>(tile + 8192 + dt * 512 + lane * 8) = w;
  }
}

// ---------------- main fused kernel: QT=64, KT=32 (R17 structure) ----------------
__global__ __launch_bounds__(256, 3) void fused_attn5(
    const float* __restrict__ Qg, const _Float16* __restrict__ Wk,
    const float* __restrict__ Sg, float* __restrict__ Og)
{
  __shared__ alignas(16) _Float16 sStage[TILE_F16];   // 24 KB: Khi|Klo|Vt
  __shared__ alignas(16) _Float16 sP[4][16][PSTR];    // 5.1 KB (wave-private)

  const int tid  = threadIdx.x;
  const int wid  = tid >> 6;
  const int lane = tid & 63;
  const int cl   = lane & 15;
  const int g8   = (lane >> 4) * 8;
  const int r0   = (lane >> 4) * 4;

  const int b  = blockIdx.x >> 5;
  const int q0 = (blockIdx.x & 31) * 64;
  const float scale = Sg[b];

  // Q A-fragments (hi/lo) in registers: rows q0+wid*16+cl
  f16x8 qhi[4], qlo[4];
  {
    const float* qp = Qg + ((size_t)b * SQ + q0 + wid * 16 + cl) * DH + g8;
#pragma unroll
    for (int ks = 0; ks < 4; ++ks) {
      const float4 a0 = *reinterpret_cast<const float4*>(qp + 32 * ks);
      const float4 a1 = *reinterpret_cast<const float4*>(qp + 32 * ks + 4);
      const float xs[8] = {a0.x, a0.y, a0.z, a0.w, a1.x, a1.y, a1.z, a1.w};
#pragma unroll
      for (int j = 0; j < 8; ++j) { qhi[ks][j] = hi16(xs[j]); qlo[ks][j] = lo16(xs[j]); }
    }
  }

  float m_run[4], l_run[4], alpha[4];
  bool  zknown[4];    // sP row currently all-zero (skip redundant zero-fills)
  f32x4 oacc[8];
#pragma unroll
  for (int i = 0; i < 4; ++i) {
    m_run[i] = -INFINITY; l_run[i] = 0.0f; zknown[i] = false;
  }
#pragma unroll
  for (int dt = 0; dt < 8; ++dt) oacc[dt] = (f32x4){0.f, 0.f, 0.f, 0.f};

  for (int kt = 0; kt < NKT; ++kt) {
    __syncthreads();   // prev iter's reads of sStage done

    // ---- DMA stage 24 KB: 24 chunks of 1 KB, 6 per wave
    const uint32_t* tsrc =
        reinterpret_cast<const uint32_t*>(Wk + (size_t)(b * NKT + kt) * TILE_F16);
#pragma unroll
    for (int c = 0; c < 6; ++c) {
      const int j = wid + 4 * c;
      __builtin_amdgcn_global_load_lds(tsrc + j * 256 + lane * 4,
          reinterpret_cast<uint32_t*>(&sStage[j * 512]), 16, 0, 0);
    }
    __syncthreads();   // tile visible

    // ---- S = Q K^T (fp16 hi/lo, fp32 accum): 16x32 per wave
    f32x4 sacc[2];
    __builtin_amdgcn_s_setprio(1);
#pragma unroll
    for (int ct = 0; ct < 2; ++ct) {
      sacc[ct] = (f32x4){0.f, 0.f, 0.f, 0.f};
#pragma unroll
      for (int ks = 0; ks < 4; ++ks) {
        const int f = ks * 2 + ct;
        const f16x8 bhi = *reinterpret_cast<const f16x8*>(&sStage[f * 512 + lane * 8]);
        const f16x8 blo = *reinterpret_cast<const f16x8*>(&sStage[4096 + f * 512 + lane * 8]);
        sacc[ct] = __builtin_amdgcn_mfma_f32_16x16x32_f16(qhi[ks], bhi, sacc[ct], 0, 0, 0);
        sacc[ct] = __builtin_amdgcn_mfma_f32_16x16x32_f16(qlo[ks], bhi, sacc[ct], 0, 0, 0);
        sacc[ct] = __builtin_amdgcn_mfma_f32_16x16x32_f16(qhi[ks], blo, sacc[ct], 0, 0, 0);
      }
    }
    __builtin_amdgcn_s_setprio(0);

    // ---- online softmax, per-row fast-path; DPP reductions (VALU pipe)
    bool anyalpha = false;
    bool tk[4];
#pragma unroll
    for (int i = 0; i < 4; ++i) {
      const float mraw = row16_max(fmaxf(sacc[0][i], sacc[1][i]));
      const float mt = mraw * scale;

      tk[i] = (mt >= m_run[i] - 9.21f);   // 16-lane-group-uniform per row
      if (tk[i]) {
        // alpha: exp only on a new record; catch-up rows give exp(0)==1 exactly
        float mnew;
        if (mt > m_run[i]) {
          alpha[i] = __expf(m_run[i] - mt);
          mnew = mt;
          m_run[i] = mt;
          anyalpha |= (alpha[i] != 1.0f);
        } else {
          alpha[i] = 1.0f;
          mnew = m_run[i];
        }
        const int qrow = q0 + wid * 16 + r0 + i;
        const uint32_t rowbase =
            ((uint32_t)b * (uint32_t)SQ + (uint32_t)qrow) * (uint32_t)SKV
            + (uint32_t)(kt * KT);

        const float t0 = sacc[0][i] * scale - mnew;
        const float t1 = sacc[1][i] * scale - mnew;
        const float p0 = __expf(t0);
        const float p1 = __expf(t1);
        const float ps = row16_sum(p0 + p1);
        l_run[i] = l_run[i] * alpha[i] + ps;

        // dropout writes with exact slab-tiny skip: t < -17.75 ->
        // (f16)(p/0.7) == 0 kept OR dropped -> threefry dead.
        if (__any(t0 >= -17.75f)) {
          const uint32_t bits = jax_random_bits(rowbase + (uint32_t)cl);
          sP[wid][r0 + i][cl] = jax_keep_bits(bits)
                                    ? (_Float16)(p0 * (1.0f / 0.7f))
                                    : (_Float16)0.0f;
        } else {
          sP[wid][r0 + i][cl] = (_Float16)0.0f;
        }
        if (__any(t1 >= -17.75f)) {
          const uint32_t bits = jax_random_bits(rowbase + (uint32_t)(16 + cl));
          sP[wid][r0 + i][16 + cl] = jax_keep_bits(bits)
                                         ? (_Float16)(p1 * (1.0f / 0.7f))
                                         : (_Float16)0.0f;
        } else {
          sP[wid][r0 + i][16 + cl] = (_Float16)0.0f;
        }
        zknown[i] = false;   // row now holds (possibly) nonzero data
      } else {
        alpha[i] = 1.0f;
      }
    }

    // ---- wave-uniform all-skip: P-tile exactly zero -> PV adds nothing.
    const int myAllSkip = !(tk[0] || tk[1] || tk[2] || tk[3]);
    if (!__all(myAllSkip)) {
      // zero-fill skipped rows only if not already zero from a prior iter
#pragma unroll
      for (int i = 0; i < 4; ++i) {
        if (!tk[i] && !zknown[i]) {
#pragma unroll
          for (int ct = 0; ct < 2; ++ct)
            sP[wid][r0 + i][16 * ct + cl] = (_Float16)0.0f;
          zknown[i] = true;
        }
      }

      if (anyalpha) {
#pragma unroll
        for (int dt = 0; dt < 8; ++dt)
#pragma unroll
          for (int i = 0; i < 4; ++i) oacc[dt][i] *= alpha[i];
      }

      // ---- O += P V (k=32, one MFMA per dt); sP wave-private
      const f16x8 pa = *reinterpret_cast<const f16x8*>(&sP[wid][cl][g8]);
      __builtin_amdgcn_s_setprio(1);
#pragma unroll
      for (int dt = 0; dt < 8; ++dt) {
        const f16x8 bv = *reinterpret_cast<const f16x8*>(
            &sStage[8192 + dt * 512 + lane * 8]);
        oacc[dt] = __builtin_amdgcn_mfma_f32_16x16x32_f16(pa, bv, oacc[dt], 0, 0, 0);
      }
      __builtin_amdgcn_s_setprio(0);
    }
  }

  // ---- epilogue
#pragma unroll
  for (int i = 0; i < 4; ++i) {
    const float inv_l = 1.0f / l_run[i];
    float* op = Og + ((size_t)b * SQ + (size_t)(q0 + wid * 16 + r0 + i)) * DH + cl;
#pragma unroll
    for (int dt = 0; dt < 8; ++dt)
      op[16 * dt] = oacc[dt][i] * inv_l;
  }
}

// ---------------- fallback (self-staging, QT=64, KT=64) ----------------
namespace {
constexpr int FKT  = 64;
constexpr int KSTR = DH + 8;
constexpr int VSTR = FKT + 8;
constexpr int FPSTR = FKT + 8;
}

__global__ __launch_bounds__(256, 2) void fused_attn_fb(
    const float* __restrict__ Qg, const float* __restrict__ Kg,
    const float* __restrict__ Vg, const float* __restrict__ Sg,
    float* __restrict__ Og)
{
  __shared__ alignas(16) _Float16 sKhi[FKT][KSTR];
  __shared__ alignas(16) _Float16 sKlo[FKT][KSTR];
  __shared__ alignas(16) _Float16 sVt[DH][VSTR];
  __shared__ alignas(16) _Float16 sP[4][16][FPSTR];

  const int tid  = threadIdx.x;
  const int wid  = tid >> 6;
  const int lane = tid & 63;
  const int cl   = lane & 15;
  const int g8   = (lane >> 4) * 8;
  const int r0   = (lane >> 4) * 4;

  const int b  = blockIdx.x >> 5;
  const int q0 = (blockIdx.x & 31) * 64;
  const float scale = Sg[b];

  f16x8 qhi[4], qlo[4];
  {
    const float* qp = Qg + ((size_t)b * SQ + q0 + wid * 16 + cl) * DH + g8;
#pragma unroll
    for (int ks = 0; ks < 4; ++ks) {
      const float4 a0 = *reinterpret_cast<const float4*>(qp + 32 * ks);
      const float4 a1 = *reinterpret_cast<const float4*>(qp + 32 * ks + 4);
      const float xs[8] = {a0.x, a0.y, a0.z, a0.w, a1.x, a1.y, a1.z, a1.w};
#pragma unroll
      for (int j = 0; j < 8; ++j) { qhi[ks][j] = hi16(xs[j]); qlo[ks][j] = lo16(xs[j]); }
    }
  }

  float m_run[4], l_run[4], alpha[4];
  f32x4 oacc[8];
#pragma unroll
  for (int i = 0; i < 4; ++i) { m_run[i] = -INFINITY; l_run[i] = 0.0f; }
#pragma unroll
  for (int dt = 0; dt < 8; ++dt) oacc[dt] = (f32x4){0.f, 0.f, 0.f, 0.f};

  for (int k0 = 0; k0 < SKV; k0 += FKT) {
    __syncthreads();
#pragma unroll
    for (int rep = 0; rep < 8; ++rep) {
      const int idx = tid + 256 * rep;
      const int row = idx >> 5;
      const int c4  = idx & 31;
      const float4 t = *reinterpret_cast<const float4*>(
          Kg + ((size_t)b * SKV + k0 + row) * DH + 4 * c4);
      f16x4 h4, l4;
      h4[0] = hi16(t.x); l4[0] = lo16(t.x);
      h4[1] = hi16(t.y); l4[1] = lo16(t.y);
      h4[2] = hi16(t.z); l4[2] = lo16(t.z);
      h4[3] = hi16(t.w); l4[3] = lo16(t.w);
      *reinterpret_cast<f16x4*>(&sKhi[row][4 * c4]) = h4;
      *reinterpret_cast<f16x4*>(&sKlo[row][4 * c4]) = l4;
    }
#pragma unroll
    for (int rep = 0; rep < 2; ++rep) {
      const int u  = tid + 256 * rep;
      const int du = u & 31;
      const int ku = u >> 5;
      const float* vb = Vg + ((size_t)b * SKV + k0 + 4 * ku) * DH + 4 * du;
      float4 t[4];
#pragma unroll
      for (int j = 0; j < 4; ++j)
        t[j] = *reinterpret_cast<const float4*>(vb + (size_t)j * DH);
#pragma unroll
      for (int dd = 0; dd < 4; ++dd) {
        const float v0 = (&t[0].x)[dd], v1 = (&t[1].x)[dd],
                    v2 = (&t[2].x)[dd], v3 = (&t[3].x)[dd];
        f16x4 w4 = {(_Float16)v0, (_Float16)v1, (_Float16)v2, (_Float16)v3};
        *reinterpret_cast<f16x4*>(&sVt[4 * du + dd][4 * ku]) = w4;
      }
    }
    __syncthreads();

    f32x4 sacc[4];
#pragma unroll
    for (int ct = 0; ct < 4; ++ct) {
      sacc[ct] = (f32x4){0.f, 0.f, 0.f, 0.f};
#pragma unroll
      for (int ks = 0; ks < 4; ++ks) {
        const f16x8 bhi = *reinterpret_cast<const f16x8*>(&sKhi[16 * ct + cl][32 * ks + g8]);
        const f16x8 blo = *reinterpret_cast<const f16x8*>(&sKlo[16 * ct + cl][32 * ks + g8]);
        sacc[ct] = __builtin_amdgcn_mfma_f32_16x16x32_f16(qhi[ks], bhi, sacc[ct], 0, 0, 0);
        sacc[ct] = __builtin_amdgcn_mfma_f32_16x16x32_f16(qlo[ks], bhi, sacc[ct], 0, 0, 0);
        sacc[ct] = __builtin_amdgcn_mfma_f32_16x16x32_f16(qhi[ks], blo, sacc[ct], 0, 0, 0);
      }
    }

    bool anyalpha = false;
#pragma unroll
    for (int i = 0; i < 4; ++i) {
      float mraw = fmaxf(fmaxf(sacc[0][i], sacc[1][i]), fmaxf(sacc[2][i], sacc[3][i]));
#pragma unroll
      for (int off = 8; off >= 1; off >>= 1)
        mraw = fmaxf(mraw, __shfl_xor(mraw, off, 64));
      const float mt = mraw * scale;
      if (mt >= m_run[i] - 9.21f) {
        const float mnew = fmaxf(m_run[i], mt);
        alpha[i] = __expf(m_run[i] - mnew);
        m_run[i] = mnew;
        const int qrow = q0 + wid * 16 + r0 + i;
        const uint32_t rowbase =
            ((uint32_t)b * (uint32_t)SQ + (uint32_t)qrow) * (uint32_t)SKV + (uint32_t)k0;
        float ps = 0.0f;
#pragma unroll
        for (int ct = 0; ct < 4; ++ct) {
          const float p = __expf(sacc[ct][i] * scale - mnew);
          ps += p;
          const bool keep = jax_keep_bits(jax_random_bits(rowbase + (uint32_t)(16 * ct + cl)));
          sP[wid][r0 + i][16 * ct + cl] = keep ? (_Float16)(p * (1.0f / 0.7f))
                                               : (_Float16)0.0f;
        }
#pragma unroll
        for (int off = 8; off >= 1; off >>= 1)
          ps += __shfl_xor(ps, off, 64);
        l_run[i] = l_run[i] * alpha[i] + ps;
        anyalpha |= (alpha[i] != 1.0f);
      } else {
        alpha[i] = 1.0f;
#pragma unroll
        for (int ct = 0; ct < 4; ++ct)
          sP[wid][r0 + i][16 * ct + cl] = (_Float16)0.0f;
      }
    }

    if (anyalpha) {
#pragma unroll
      for (int dt = 0; dt < 8; ++dt)
#pragma unroll
        for (int i = 0; i < 4; ++i) oacc[dt][i] *= alpha[i];
    }
#pragma unroll
    for (int ks2 = 0; ks2 < 2; ++ks2) {
      const f16x8 pa = *reinterpret_cast<const f16x8*>(&sP[wid][cl][32 * ks2 + g8]);
#pragma unroll
      for (int dt = 0; dt < 8; ++dt) {
        const f16x8 bv = *reinterpret_cast<const f16x8*>(&sVt[16 * dt + cl][32 * ks2 + g8]);
        oacc[dt] = __builtin_amdgcn_mfma_f32_16x16x32_f16(pa, bv, oacc[dt], 0, 0, 0);
      }
    }
  }

#pragma unroll
  for (int i = 0; i < 4; ++i) {
    const float inv_l = 1.0f / l_run[i];
    float* op = Og + ((size_t)b * SQ + (size_t)(q0 + wid * 16 + r0 + i)) * DH + cl;
#pragma unroll
    for (int dt = 0; dt < 8; ++dt)
      op[16 * dt] = oacc[dt][i] * inv_l;
  }
}

extern "C" void kernel_launch(void* const* d_in, const int* in_sizes, int n_in,
                              void* d_out, int out_size, void* d_ws, size_t ws_size,
                              hipStream_t stream) {
  (void)in_sizes; (void)n_in; (void)out_size;
  const float* q  = (const float*)d_in[0];
  const float* k  = (const float*)d_in[1];
  const float* v  = (const float*)d_in[2];
  const float* sc = (const float*)d_in[3];
  float* out = (float*)d_out;

  if (ws_size >= WS_NEED) {
    _Float16* ws = (_Float16*)d_ws;
    prep_tile<<<dim3(Bb * NKT), dim3(256), 0, stream>>>(k, v, ws);
    fused_attn5<<<dim3(Bb * (SQ / 64)), dim3(256), 0, stream>>>(q, ws, sc, out);
  } else {
    fused_attn_fb<<<dim3(Bb * (SQ / 64)), dim3(256), 0, stream>>>(q, k, v, sc, out);
  }
}

// Round 13
// 319.705 us; speedup vs baseline: 1.0787x; 1.0001x over previous
//
#include <hip/hip_runtime.h>
#include <stdint.h>

// R21: fused kernel == R18/R20 verbatim (224us, structure pinned by five
// falsified deviations). Prepass restructured to attack the ~95us e2e-kernel
// gap (30% of e2e; proven prepass-variable by R12/R17 deltas): single-phase
// prep_tile -- K AND V tiles DMA'd via global_load_lds (width 16) into
// linear [32][128] f32 LDS (32KB, 5 blocks/CU), ONE barrier (vs 3), then
// both transforms back-to-back. Linear LDS required by global_load_lds
// wave-uniform-dest; transform-read bank conflicts evidenced-null (R18
// swizzle A/B). Same arithmetic -> bit-exact; absmax must stay 0.03125.

namespace {

constexpr int Bb  = 32;
constexpr int SQ  = 2048;
constexpr int SKV = 2048;
constexpr int DH  = 128;
constexpr int KT  = 32;
constexpr int NKT = SKV / KT;          // 64
constexpr int TILE_F16 = 12288;        // Khi 4096 | Klo 4096 | Vt 4096 (f16 elems)
constexpr size_t WS_NEED = (size_t)Bb * NKT * TILE_F16 * 2;  // 50,331,648 B
constexpr int PSTR = KT + 8;           // 40

typedef _Float16 f16x8 __attribute__((ext_vector_type(8)));
typedef _Float16 f16x4 __attribute__((ext_vector_type(4)));
typedef float    f32x4 __attribute__((ext_vector_type(4)));

__device__ __forceinline__ uint32_t rotl32(uint32_t x, int d) {
  return (x << d) | (x >> (32 - d));
}

// JAX threefry2x32, key=(0,42), counter=(0,i); partitionable bits = x0^x1.
__device__ __forceinline__ uint32_t jax_random_bits(uint32_t i) {
  constexpr uint32_t K0 = 0u;
  constexpr uint32_t K1 = 42u;
  constexpr uint32_t K2 = 0x1BD11BDAu ^ K0 ^ K1;
  uint32_t x0 = K0;
  uint32_t x1 = i + K1;
#define TF4(a,b,c,d) \
  x0 += x1; x1 = rotl32(x1,a); x1 ^= x0; \
  x0 += x1; x1 = rotl32(x1,b); x1 ^= x0; \
  x0 += x1; x1 = rotl32(x1,c); x1 ^= x0; \
  x0 += x1; x1 = rotl32(x1,d); x1 ^= x0;
  TF4(13,15,26,6)   x0 += K1; x1 += K2 + 1u;
  TF4(17,29,16,24)  x0 += K2; x1 += K0 + 2u;
  TF4(13,15,26,6)   x0 += K0; x1 += K1 + 3u;
  TF4(17,29,16,24)  x0 += K1; x1 += K2 + 4u;
  TF4(13,15,26,6)   x0 += K2; x1 += K0 + 5u;
#undef TF4
  return x0 ^ x1;
}

// keep <=> uniform < 0.7f  <=>  (bits>>9) < 0x59999A  (exact)
__device__ __forceinline__ bool jax_keep_bits(uint32_t bits) {
  return (bits >> 9) < 0x0059999Au;
}

__device__ __forceinline__ _Float16 hi16(float x) { return (_Float16)x; }
__device__ __forceinline__ _Float16 lo16(float x) {
  return (_Float16)(x - (float)((_Float16)x));
}

// DPP lane-permute (VALU pipe; stays within 16-lane row, all sources active
// under the row-uniform branch). bound_ctrl=1, full row/bank masks.
template <int CTRL>
__device__ __forceinline__ float dppf(float v) {
  return __int_as_float(__builtin_amdgcn_update_dpp(
      0, __float_as_int(v), CTRL, 0xF, 0xF, true));
}
__device__ __forceinline__ float row16_max(float x) {
  x = fmaxf(x, dppf<0xB1>(x));
  x = fmaxf(x, dppf<0x4E>(x));
  x = fmaxf(x, dppf<0x141>(x));
  x = fmaxf(x, dppf<0x140>(x));
  return x;
}
__device__ __forceinline__ float row16_sum(float x) {
  x += dppf<0xB1>(x);
  x += dppf<0x4E>(x);
  x += dppf<0x141>(x);
  x += dppf<0x140>(x);
  return x;
}

} // namespace

// ------------- prepass v3: single phase, async DMA loads, one barrier -------------
__global__ __launch_bounds__(256) void prep_tile(const float* __restrict__ Kg,
                                                 const float* __restrict__ Vg,
                                                 _Float16* __restrict__ ws) {
  // linear layouts (required by global_load_lds wave-uniform dest)
  __shared__ alignas(16) float sK[KT][DH];   // 16 KB
  __shared__ alignas(16) float sV[KT][DH];   // 16 KB

  const int tid  = threadIdx.x;
  const int wid  = tid >> 6;
  const int lane = tid & 63;
  const int b    = blockIdx.x >> 6;
  const int kt   = blockIdx.x & 63;
  _Float16* tile = ws + (size_t)(b * NKT + kt) * TILE_F16;

  // ---- issue ALL loads: 16 KB K + 16 KB V = 32 chunks of 1 KB, 8 per wave
  {
    const uint32_t* kb =
        reinterpret_cast<const uint32_t*>(Kg + ((size_t)b * SKV + kt * KT) * DH);
    const uint32_t* vb =
        reinterpret_cast<const uint32_t*>(Vg + ((size_t)b * SKV + kt * KT) * DH);
    uint32_t* sKu = reinterpret_cast<uint32_t*>(&sK[0][0]);
    uint32_t* sVu = reinterpret_cast<uint32_t*>(&sV[0][0]);
#pragma unroll
    for (int c = 0; c < 4; ++c) {
      const int j = wid + 4 * c;   // 0..15
      __builtin_amdgcn_global_load_lds(kb + j * 256 + lane * 4,
                                       sKu + j * 256, 16, 0, 0);
    }
#pragma unroll
    for (int c = 0; c < 4; ++c) {
      const int j = wid + 4 * c;   // 0..15
      __builtin_amdgcn_global_load_lds(vb + j * 256 + lane * 4,
                                       sVu + j * 256, 16, 0, 0);
    }
  }
  __syncthreads();   // single barrier: compiler drains vmcnt before it

  // ---- transform K: hi/lo fragment-linear writes, frag f = ks*2+ct (0..7)
#pragma unroll
  for (int rep = 0; rep < 2; ++rep) {
    const int task = tid + 256 * rep;     // 0..511
    const int l    = task & 63;
    const int f    = task >> 6;           // 0..7
    const int ks   = f >> 1;
    const int ct   = f & 1;
    const int cl   = l & 15;
    const int g8   = (l >> 4) * 8;
    const float* src = &sK[ct * 16 + cl][ks * 32 + g8];
    f16x8 h, lo;
#pragma unroll
    for (int j = 0; j < 8; ++j) { h[j] = hi16(src[j]); lo[j] = lo16(src[j]); }
    *reinterpret_cast<f16x8*>(tile + f * 512 + l * 8)        = h;
    *reinterpret_cast<f16x8*>(tile + 4096 + f * 512 + l * 8) = lo;
  }

  // ---- transform V^T: frag = dt (0..7), elem j = V[g8+j][dt*16+cl]
#pragma unroll
  for (int rep = 0; rep < 2; ++rep) {
    const int task = tid + 256 * rep;
    const int l    = task & 63;
    const int dt   = task >> 6;           // 0..7
    const int cl   = l & 15;
    const int g8   = (l >> 4) * 8;
    f16x8 w;
#pragma unroll
    for (int j = 0; j < 8; ++j)
      w[j] = (_Float16)sV[g8 + j][dt * 16 + cl];
    *reinterpret_cast<f16x8*>(tile + 8192 + dt * 512 + l * 8) = w;
  }
}

// ---------------- main fused kernel: QT=64, KT=32 (R18/R20 verbatim) ----------------
__global__ __launch_bounds__(256, 3) void fused_attn5(
    const float* __restrict__ Qg, const _Float16* __restrict__ Wk,
    const float* __restrict__ Sg, float* __restrict__ Og)
{
  __shared__ alignas(16) _Float16 sStage[TILE_F16];   // 24 KB: Khi|Klo|Vt
  __shared__ alignas(16) _Float16 sP[4][16][PSTR];    // 5.1 KB (wave-private)

  const int tid  = threadIdx.x;
  const int wid  = tid >> 6;
  const int lane = tid & 63;
  const int cl   = lane & 15;
  const int g8   = (lane >> 4) * 8;
  const int r0   = (lane >> 4) * 4;

  const int b  = blockIdx.x >> 5;
  const int q0 = (blockIdx.x & 31) * 64;
  const float scale = Sg[b];

  // Q A-fragments (hi/lo) in registers: rows q0+wid*16+cl
  f16x8 qhi[4], qlo[4];
  {
    const float* qp = Qg + ((size_t)b * SQ + q0 + wid * 16 + cl) * DH + g8;
#pragma unroll
    for (int ks = 0; ks < 4; ++ks) {
      const float4 a0 = *reinterpret_cast<const float4*>(qp + 32 * ks);
      const float4 a1 = *reinterpret_cast<const float4*>(qp + 32 * ks + 4);
      const float xs[8] = {a0.x, a0.y, a0.z, a0.w, a1.x, a1.y, a1.z, a1.w};
#pragma unroll
      for (int j = 0; j < 8; ++j) { qhi[ks][j] = hi16(xs[j]); qlo[ks][j] = lo16(xs[j]); }
    }
  }

  float m_run[4], l_run[4], alpha[4];
  bool  zknown[4];    // sP row currently all-zero (skip redundant zero-fills)
  f32x4 oacc[8];
#pragma unroll
  for (int i = 0; i < 4; ++i) {
    m_run[i] = -INFINITY; l_run[i] = 0.0f; zknown[i] = false;
  }
#pragma unroll
  for (int dt = 0; dt < 8; ++dt) oacc[dt] = (f32x4){0.f, 0.f, 0.f, 0.f};

  for (int kt = 0; kt < NKT; ++kt) {
    __syncthreads();   // prev iter's reads of sStage done

    // ---- DMA stage 24 KB: 24 chunks of 1 KB, 6 per wave
    const uint32_t* tsrc =
        reinterpret_cast<const uint32_t*>(Wk + (size_t)(b * NKT + kt) * TILE_F16);
#pragma unroll
    for (int c = 0; c < 6; ++c) {
      const int j = wid + 4 * c;
      __builtin_amdgcn_global_load_lds(tsrc + j * 256 + lane * 4,
          reinterpret_cast<uint32_t*>(&sStage[j * 512]), 16, 0, 0);
    }
    __syncthreads();   // tile visible

    // ---- S = Q K^T (fp16 hi/lo, fp32 accum): 16x32 per wave
    f32x4 sacc[2];
    __builtin_amdgcn_s_setprio(1);
#pragma unroll
    for (int ct = 0; ct < 2; ++ct) {
      sacc[ct] = (f32x4){0.f, 0.f, 0.f, 0.f};
#pragma unroll
      for (int ks = 0; ks < 4; ++ks) {
        const int f = ks * 2 + ct;
        const f16x8 bhi = *reinterpret_cast<const f16x8*>(&sStage[f * 512 + lane * 8]);
        const f16x8 blo = *reinterpret_cast<const f16x8*>(&sStage[4096 + f * 512 + lane * 8]);
        sacc[ct] = __builtin_amdgcn_mfma_f32_16x16x32_f16(qhi[ks], bhi, sacc[ct], 0, 0, 0);
        sacc[ct] = __builtin_amdgcn_mfma_f32_16x16x32_f16(qlo[ks], bhi, sacc[ct], 0, 0, 0);
        sacc[ct] = __builtin_amdgcn_mfma_f32_16x16x32_f16(qhi[ks], blo, sacc[ct], 0, 0, 0);
      }
    }
    __builtin_amdgcn_s_setprio(0);

    // ---- online softmax, per-row fast-path; DPP reductions (VALU pipe)
    bool anyalpha = false;
    bool tk[4];
#pragma unroll
    for (int i = 0; i < 4; ++i) {
      const float mraw = row16_max(fmaxf(sacc[0][i], sacc[1][i]));
      const float mt = mraw * scale;

      tk[i] = (mt >= m_run[i] - 9.21f);   // 16-lane-group-uniform per row
      if (tk[i]) {
        // alpha: exp only on a new record; catch-up rows give exp(0)==1 exactly
        float mnew;
        if (mt > m_run[i]) {
          alpha[i] = __expf(m_run[i] - mt);
          mnew = mt;
          m_run[i] = mt;
          anyalpha |= (alpha[i] != 1.0f);
        } else {
          alpha[i] = 1.0f;
          mnew = m_run[i];
        }
        const int qrow = q0 + wid * 16 + r0 + i;
        const uint32_t rowbase =
            ((uint32_t)b * (uint32_t)SQ + (uint32_t)qrow) * (uint32_t)SKV
            + (uint32_t)(kt * KT);

        const float t0 = sacc[0][i] * scale - mnew;
        const float t1 = sacc[1][i] * scale - mnew;
        const float p0 = __expf(t0);
        const float p1 = __expf(t1);
        const float ps = row16_sum(p0 + p1);
        l_run[i] = l_run[i] * alpha[i] + ps;

        // dropout writes with exact slab-tiny skip: t < -17.75 ->
        // (f16)(p/0.7) == 0 kept OR dropped -> threefry dead.
        if (__any(t0 >= -17.75f)) {
          const uint32_t bits = jax_random_bits(rowbase + (uint32_t)cl);
          sP[wid][r0 + i][cl] = jax_keep_bits(bits)
                                    ? (_Float16)(p0 * (1.0f / 0.7f))
                                    : (_Float16)0.0f;
        } else {
          sP[wid][r0 + i][cl] = (_Float16)0.0f;
        }
        if (__any(t1 >= -17.75f)) {
          const uint32_t bits = jax_random_bits(rowbase + (uint32_t)(16 + cl));
          sP[wid][r0 + i][16 + cl] = jax_keep_bits(bits)
                                         ? (_Float16)(p1 * (1.0f / 0.7f))
                                         : (_Float16)0.0f;
        } else {
          sP[wid][r0 + i][16 + cl] = (_Float16)0.0f;
        }
        zknown[i] = false;   // row now holds (possibly) nonzero data
      } else {
        alpha[i] = 1.0f;
      }
    }

    // ---- wave-uniform all-skip: P-tile exactly zero -> PV adds nothing.
    const int myAllSkip = !(tk[0] || tk[1] || tk[2] || tk[3]);
    if (!__all(myAllSkip)) {
      // zero-fill skipped rows only if not already zero from a prior iter
#pragma unroll
      for (int i = 0; i < 4; ++i) {
        if (!tk[i] && !zknown[i]) {
#pragma unroll
          for (int ct = 0; ct < 2; ++ct)
            sP[wid][r0 + i][16 * ct + cl] = (_Float16)0.0f;
          zknown[i] = true;
        }
      }

      if (anyalpha) {
#pragma unroll
        for (int dt = 0; dt < 8; ++dt)
#pragma unroll
          for (int i = 0; i < 4; ++i) oacc[dt][i] *= alpha[i];
      }

      // ---- O += P V (k=32, one MFMA per dt); sP wave-private
      const f16x8 pa = *reinterpret_cast<const f16x8*>(&sP[wid][cl][g8]);
      __builtin_amdgcn_s_setprio(1);
#pragma unroll
      for (int dt = 0; dt < 8; ++dt) {
        const f16x8 bv = *reinterpret_cast<const f16x8*>(
            &sStage[8192 + dt * 512 + lane * 8]);
        oacc[dt] = __builtin_amdgcn_mfma_f32_16x16x32_f16(pa, bv, oacc[dt], 0, 0, 0);
      }
      __builtin_amdgcn_s_setprio(0);
    }
  }

  // ---- epilogue
#pragma unroll
  for (int i = 0; i < 4; ++i) {
    const float inv_l = 1.0f / l_run[i];
    float* op = Og + ((size_t)b * SQ + (size_t)(q0 + wid * 16 + r0 + i)) * DH + cl;
#pragma unroll
    for (int dt = 0; dt < 8; ++dt)
      op[16 * dt] = oacc[dt][i] * inv_l;
  }
}

// ---------------- fallback (self-staging, QT=64, KT=64) ----------------
namespace {
constexpr int FKT  = 64;
constexpr int KSTR = DH + 8;
constexpr int VSTR = FKT + 8;
constexpr int FPSTR = FKT + 8;
}

__global__ __launch_bounds__(256, 2) void fused_attn_fb(
    const float* __restrict__ Qg, const float* __restrict__ Kg,
    const float* __restrict__ Vg, const float* __restrict__ Sg,
    float* __restrict__ Og)
{
  __shared__ alignas(16) _Float16 sKhi[FKT][KSTR];
  __shared__ alignas(16) _Float16 sKlo[FKT][KSTR];
  __shared__ alignas(16) _Float16 sVt[DH][VSTR];
  __shared__ alignas(16) _Float16 sP[4][16][FPSTR];

  const int tid  = threadIdx.x;
  const int wid  = tid >> 6;
  const int lane = tid & 63;
  const int cl   = lane & 15;
  const int g8   = (lane >> 4) * 8;
  const int r0   = (lane >> 4) * 4;

  const int b  = blockIdx.x >> 5;
  const int q0 = (blockIdx.x & 31) * 64;
  const float scale = Sg[b];

  f16x8 qhi[4], qlo[4];
  {
    const float* qp = Qg + ((size_t)b * SQ + q0 + wid * 16 + cl) * DH + g8;
#pragma unroll
    for (int ks = 0; ks < 4; ++ks) {
      const float4 a0 = *reinterpret_cast<const float4*>(qp + 32 * ks);
      const float4 a1 = *reinterpret_cast<const float4*>(qp + 32 * ks + 4);
      const float xs[8] = {a0.x, a0.y, a0.z, a0.w, a1.x, a1.y, a1.z, a1.w};
#pragma unroll
      for (int j = 0; j < 8; ++j) { qhi[ks][j] = hi16(xs[j]); qlo[ks][j] = lo16(xs[j]); }
    }
  }

  float m_run[4], l_run[4], alpha[4];
  f32x4 oacc[8];
#pragma unroll
  for (int i = 0; i < 4; ++i) { m_run[i] = -INFINITY; l_run[i] = 0.0f; }
#pragma unroll
  for (int dt = 0; dt < 8; ++dt) oacc[dt] = (f32x4){0.f, 0.f, 0.f, 0.f};

  for (int k0 = 0; k0 < SKV; k0 += FKT) {
    __syncthreads();
#pragma unroll
    for (int rep = 0; rep < 8; ++rep) {
      const int idx = tid + 256 * rep;
      const int row = idx >> 5;
      const int c4  = idx & 31;
      const float4 t = *reinterpret_cast<const float4*>(
          Kg + ((size_t)b * SKV + k0 + row) * DH + 4 * c4);
      f16x4 h4, l4;
      h4[0] = hi16(t.x); l4[0] = lo16(t.x);
      h4[1] = hi16(t.y); l4[1] = lo16(t.y);
      h4[2] = hi16(t.z); l4[2] = lo16(t.z);
      h4[3] = hi16(t.w); l4[3] = lo16(t.w);
      *reinterpret_cast<f16x4*>(&sKhi[row][4 * c4]) = h4;
      *reinterpret_cast<f16x4*>(&sKlo[row][4 * c4]) = l4;
    }
#pragma unroll
    for (int rep = 0; rep < 2; ++rep) {
      const int u  = tid + 256 * rep;
      const int du = u & 31;
      const int ku = u >> 5;
      const float* vb = Vg + ((size_t)b * SKV + k0 + 4 * ku) * DH + 4 * du;
      float4 t[4];
#pragma unroll
      for (int j = 0; j < 4; ++j)
        t[j] = *reinterpret_cast<const float4*>(vb + (size_t)j * DH);
#pragma unroll
      for (int dd = 0; dd < 4; ++dd) {
        const float v0 = (&t[0].x)[dd], v1 = (&t[1].x)[dd],
                    v2 = (&t[2].x)[dd], v3 = (&t[3].x)[dd];
        f16x4 w4 = {(_Float16)v0, (_Float16)v1, (_Float16)v2, (_Float16)v3};
        *reinterpret_cast<f16x4*>(&sVt[4 * du + dd][4 * ku]) = w4;
      }
    }
    __syncthreads();

    f32x4 sacc[4];
#pragma unroll
    for (int ct = 0; ct < 4; ++ct) {
      sacc[ct] = (f32x4){0.f, 0.f, 0.f, 0.f};
#pragma unroll
      for (int ks = 0; ks < 4; ++ks) {
        const f16x8 bhi = *reinterpret_cast<const f16x8*>(&sKhi[16 * ct + cl][32 * ks + g8]);
        const f16x8 blo = *reinterpret_cast<const f16x8*>(&sKlo[16 * ct + cl][32 * ks + g8]);
        sacc[ct] = __builtin_amdgcn_mfma_f32_16x16x32_f16(qhi[ks], bhi, sacc[ct], 0, 0, 0);
        sacc[ct] = __builtin_amdgcn_mfma_f32_16x16x32_f16(qlo[ks], bhi, sacc[ct], 0, 0, 0);
        sacc[ct] = __builtin_amdgcn_mfma_f32_16x16x32_f16(qhi[ks], blo, sacc[ct], 0, 0, 0);
      }
    }

    bool anyalpha = false;
#pragma unroll
    for (int i = 0; i < 4; ++i) {
      float mraw = fmaxf(fmaxf(sacc[0][i], sacc[1][i]), fmaxf(sacc[2][i], sacc[3][i]));
#pragma unroll
      for (int off = 8; off >= 1; off >>= 1)
        mraw = fmaxf(mraw, __shfl_xor(mraw, off, 64));
      const float mt = mraw * scale;
      if (mt >= m_run[i] - 9.21f) {
        const float mnew = fmaxf(m_run[i], mt);
        alpha[i] = __expf(m_run[i] - mnew);
        m_run[i] = mnew;
        const int qrow = q0 + wid * 16 + r0 + i;
        const uint32_t rowbase =
            ((uint32_t)b * (uint32_t)SQ + (uint32_t)qrow) * (uint32_t)SKV + (uint32_t)k0;
        float ps = 0.0f;
#pragma unroll
        for (int ct = 0; ct < 4; ++ct) {
          const float p = __expf(sacc[ct][i] * scale - mnew);
          ps += p;
          const bool keep = jax_keep_bits(jax_random_bits(rowbase + (uint32_t)(16 * ct + cl)));
          sP[wid][r0 + i][16 * ct + cl] = keep ? (_Float16)(p * (1.0f / 0.7f))
                                               : (_Float16)0.0f;
        }
#pragma unroll
        for (int off = 8; off >= 1; off >>= 1)
          ps += __shfl_xor(ps, off, 64);
        l_run[i] = l_run[i] * alpha[i] + ps;
        anyalpha |= (alpha[i] != 1.0f);
      } else {
        alpha[i] = 1.0f;
#pragma unroll
        for (int ct = 0; ct < 4; ++ct)
          sP[wid][r0 + i][16 * ct + cl] = (_Float16)0.0f;
      }
    }

    if (anyalpha) {
#pragma unroll
      for (int dt = 0; dt < 8; ++dt)
#pragma unroll
        for (int i = 0; i < 4; ++i) oacc[dt][i] *= alpha[i];
    }
#pragma unroll
    for (int ks2 = 0; ks2 < 2; ++ks2) {
      const f16x8 pa = *reinterpret_cast<const f16x8*>(&sP[wid][cl][32 * ks2 + g8]);
#pragma unroll
      for (int dt = 0; dt < 8; ++dt) {
        const f16x8 bv = *reinterpret_cast<const f16x8*>(&sVt[16 * dt + cl][32 * ks2 + g8]);
        oacc[dt] = __builtin_amdgcn_mfma_f32_16x16x32_f16(pa, bv, oacc[dt], 0, 0, 0);
      }
    }
  }

#pragma unroll
  for (int i = 0; i < 4; ++i) {
    const float inv_l = 1.0f / l_run[i];
    float* op = Og + ((size_t)b * SQ + (size_t)(q0 + wid * 16 + r0 + i)) * DH + cl;
#pragma unroll
    for (int dt = 0; dt < 8; ++dt)
      op[16 * dt] = oacc[dt][i] * inv_l;
  }
}

extern "C" void kernel_launch(void* const* d_in, const int* in_sizes, int n_in,
                              void* d_out, int out_size, void* d_ws, size_t ws_size,
                              hipStream_t stream) {
  (void)in_sizes; (void)n_in; (void)out_size;
  const float* q  = (const float*)d_in[0];
  const float* k  = (const float*)d_in[1];
  const float* v  = (const float*)d_in[2];
  const float* sc = (const float*)d_in[3];
  float* out = (float*)d_out;

  if (ws_size >= WS_NEED) {
    _Float16* ws = (_Float16*)d_ws;
    prep_tile<<<dim3(Bb * NKT), dim3(256), 0, stream>>>(k, v, ws);
    fused_attn5<<<dim3(Bb * (SQ / 64)), dim3(256), 0, stream>>>(q, ws, sc, out);
  } else {
    fused_attn_fb<<<dim3(Bb * (SQ / 64)), dim3(256), 0, stream>>>(q, k, v, sc, out);
  }
}